// Round 1
// baseline (120.478 us; speedup 1.0000x reference)
//
#include <hip/hip_runtime.h>
#include <hip/hip_cooperative_groups.h>

namespace cg = cooperative_groups;

#define H 1024
#define W 1024
#define NPIX (H * W)
#define WW 16          // 64-row words per column
#define INF_F 1e12f
#define THREADS 256
#define BLOCKS 512     // 2 rows per block
#define BIG (1 << 29)

// ---------------------------------------------------------------------------
// Exact vertical nearest-site distance for pixel (r,c), polarity pol
// (pol=1: sites are 1-pixels; pol=0: sites are 0-pixels). Cold path.
// ---------------------------------------------------------------------------
__device__ __noinline__ int vert_dist_full(const unsigned long long* __restrict__ pw,
                                           int r, int c, int pol) {
  int w = r >> 6, b = r & 63;
  unsigned long long v = pw[w * W + c];
  unsigned long long m_c = pol ? v : ~v;
  int dup = 1 << 30, ddn = 1 << 30;
  unsigned long long am = m_c & ((1ULL << b) - 1ULL);
  if (am) {
    dup = b - (63 - __builtin_clzll(am));
  } else {
    for (int ww = w - 1; ww >= 0; --ww) {
      unsigned long long mv = pw[ww * W + c];
      mv = pol ? mv : ~mv;
      if (mv) { dup = r - (ww * 64 + 63 - __builtin_clzll(mv)); break; }
    }
  }
  unsigned long long bm = m_c >> b;  // includes self
  if (bm) {
    ddn = __builtin_ctzll(bm);
  } else {
    for (int ww = w + 1; ww < WW; ++ww) {
      unsigned long long mv = pw[ww * W + c];
      mv = pol ? mv : ~mv;
      if (mv) { ddn = (ww * 64 + __builtin_ctzll(mv)) - r; break; }
    }
  }
  return min(dup, ddn);
}

// Cold exact continuation/restart of the parabola min. Never taken at p=0.5.
__device__ __noinline__ int horiz_exact(const unsigned long long* __restrict__ pw,
                                        int r, int c, int pol, int best, int dk0) {
  for (int dk = dk0; dk < W; ++dk) {
    int dk2 = dk * dk;
    if (dk2 >= best) break;
    if (c - dk >= 0) {
      int d = vert_dist_full(pw, r, c - dk, pol);
      if (d < H) best = min(best, d * d + dk2);
    }
    if (c + dk < W) {
      int d = vert_dist_full(pw, r, c + dk, pol);
      if (d < H) best = min(best, d * d + dk2);
    }
  }
  return best;
}

// ---------------------------------------------------------------------------
// Single cooperative kernel:
//   phase 0: pack target bits (all 512 blocks participate, wave 0 of each)
//   grid.sync()
//   phase 1: vertical EDT via bit ops, 2 rows per block (rows 2q, 2q+1
//            always share the same 64-bit word => window loads amortized)
//   phase 2: horizontal parabola envelope from LDS bytes + input*sd product
//   phase 3: block reduce -> partials; device-scope counter; last block
//            reduces 512 partials and writes the mean.
// Co-residency: 512 blocks x 256 thr = 2 blocks/CU, guaranteed by
// __launch_bounds__(256,2) (VGPR<=256, LDS 4.4KB) -> coop launch succeeds.
// ---------------------------------------------------------------------------
__global__ __launch_bounds__(THREADS, 2) void fused_all(
    const int* __restrict__ target,
    const float* __restrict__ input,
    unsigned long long* __restrict__ pw,
    double* __restrict__ partials,
    unsigned int* __restrict__ count,
    float* __restrict__ out) {
  const int tid = threadIdx.x;
  const int bid = blockIdx.x;

  // counter lives in re-poisoned workspace: init before grid.sync
  if (bid == 0 && tid == 0) *count = 0u;

  // ---- phase 0: pack. 32768 u32-half-word tasks, 64 per block ----
  if (tid < 64) {
    int tg = (bid << 6) + tid;          // [0, 32768)
    int w = tg >> 11;
    int half = (tg >> 10) & 1;
    int c = tg & (W - 1);
    int rbase = w * 64 + half * 32;
    unsigned int val = 0;
#pragma unroll
    for (int b = 0; b < 32; ++b) {
      if (target[(rbase + b) * W + c] != 0) val |= (1u << b);
    }
    ((unsigned int*)pw)[((w * W + c) << 1) + half] = val;
  }

  cg::this_grid().sync();

  // byte distances, [row][pol][32 + c]; 255 = "d >= 255" sentinel / pad
  __shared__ unsigned char sd8[2][2][W + 64];
  __shared__ double smem[THREADS / 64];
  __shared__ int amLast;

  const int r0 = bid << 1;           // rows r0, r0+1
  const int w = r0 >> 6;             // same word for both rows (r0 even)
  const int b0 = r0 & 63;            // even, so b0+1 <= 63
  const int c0 = tid << 2;           // 4 consecutive columns per thread

  // border init: 4 planes x 16 pad-u32 (8 left + 8 right per plane)
  if (tid < 64) {
    int p = tid >> 4, q = tid & 15;
    ((unsigned int*)sd8)[p * 272 + (q < 8 ? q : 256 + q)] = 0xFFFFFFFFu;
  }

  // ---- phase 1: vertical distances for 4 cols, 2 rows, both polarities ----
  unsigned long long curv[4], prevv[4], nextv[4];
  *(ulonglong2*)&curv[0] = *(const ulonglong2*)(pw + w * W + c0);
  *(ulonglong2*)&curv[2] = *(const ulonglong2*)(pw + w * W + c0 + 2);
  const bool hp = (w > 0), hn = (w < WW - 1);
  if (hp) {
    *(ulonglong2*)&prevv[0] = *(const ulonglong2*)(pw + (w - 1) * W + c0);
    *(ulonglong2*)&prevv[2] = *(const ulonglong2*)(pw + (w - 1) * W + c0 + 2);
  } else prevv[0] = prevv[1] = prevv[2] = prevv[3] = 0ULL;
  if (hn) {
    *(ulonglong2*)&nextv[0] = *(const ulonglong2*)(pw + (w + 1) * W + c0);
    *(ulonglong2*)&nextv[2] = *(const ulonglong2*)(pw + (w + 1) * W + c0 + 2);
  } else nextv[0] = nextv[1] = nextv[2] = nextv[3] = 0ULL;

  unsigned char dloc[2][2][4];  // [row][pol][k]
#pragma unroll
  for (int pol = 0; pol < 2; ++pol) {
#pragma unroll
    for (int k = 0; k < 4; ++k) {
      unsigned long long m_c = pol ? curv[k] : ~curv[k];
      unsigned long long m_p = hp ? (pol ? prevv[k] : ~prevv[k]) : 0ULL;
      unsigned long long m_n = hn ? (pol ? nextv[k] : ~nextv[k]) : 0ULL;
#pragma unroll
      for (int rr = 0; rr < 2; ++rr) {
        int b = b0 + rr;
        int d = 1 << 30;
        unsigned long long am = m_c & ((1ULL << b) - 1ULL);
        if (am) d = b - (63 - __builtin_clzll(am));
        else if (m_p) d = b + 1 + __builtin_clzll(m_p);
        unsigned long long bm = m_c >> b;  // includes self
        int dd = 1 << 30;
        if (bm) dd = __builtin_ctzll(bm);
        else if (m_n) dd = (64 - b) + __builtin_ctzll(m_n);
        d = min(d, dd);
        // window-blind (both directions) must be re-resolved exactly
        if (d > 64) d = vert_dist_full(pw, r0 + rr, c0 + k, pol);  // cold
        dloc[rr][pol][k] = (unsigned char)min(d, 255);
      }
    }
  }
  // LDS store: pack 4 col-bytes -> one u32 per (row,pol); conflict-free
#pragma unroll
  for (int rr = 0; rr < 2; ++rr) {
#pragma unroll
    for (int pol = 0; pol < 2; ++pol) {
      unsigned int u = (unsigned int)dloc[rr][pol][0] |
                       ((unsigned int)dloc[rr][pol][1] << 8) |
                       ((unsigned int)dloc[rr][pol][2] << 16) |
                       ((unsigned int)dloc[rr][pol][3] << 24);
      *(unsigned int*)&sd8[rr][pol][32 + c0] = u;
    }
  }
  __syncthreads();

  // ---- phase 2: horizontal envelope + product, both rows ----
  double val = 0.0;
#pragma unroll
  for (int rr = 0; rr < 2; ++rr) {
    const int r = r0 + rr;
    const float4 iv = *(const float4*)(input + r * W + c0);
    const float ivk[4] = {iv.x, iv.y, iv.z, iv.w};
#pragma unroll
    for (int k = 0; k < 4; ++k) {
      const bool t = (dloc[rr][1][k] == 0);  // nearest-one dist 0 <=> t=1
      const int pol = t ? 0 : 1;             // t uses g_t (nearest zero)
      const int own = dloc[rr][pol][k];
      int best = (own == 255) ? BIG : own * own;
      const unsigned char* __restrict__ sg = &sd8[rr][pol][32 + c0 + k];
#pragma unroll
      for (int dk = 1; dk <= 2; ++dk) {  // branchless probes, exactness-safe
        int dl = sg[-dk], dr = sg[dk];
        int gl = (dl == 255) ? BIG : dl * dl;
        int gr = (dr == 255) ? BIG : dr * dr;
        best = min(best, min(gl, gr) + dk * dk);
      }
      for (int dk = 3; dk <= 32; ++dk) {
        int dk2 = dk * dk;
        if (dk2 >= best) break;
        int dl = sg[-dk], dr = sg[dk];
        int gl = (dl == 255) ? BIG : dl * dl;
        int gr = (dr == 255) ? BIG : dr * dr;
        best = min(best, min(gl, gr) + dk2);
      }
      if (best > 1089) {  // cold exact fallback (beyond halo / sentinel)
        int c = c0 + k;
        if (best > 65025) {  // 255-sentinel could have hidden a true min
          int ov = vert_dist_full(pw, r, c, pol);
          best = (ov < H) ? ov * ov : (1 << 30);
          best = horiz_exact(pw, r, c, pol, best, 1);
        } else {
          best = horiz_exact(pw, r, c, pol, best, 33);
        }
      }
      float bestf = (best >= BIG) ? INF_F : (float)best;
      float dist = sqrtf(bestf);
      float sd = t ? (1.0f - dist) : dist;
      val += (double)(ivk[k] * sd);
    }
  }

  // ---- phase 3: block reduction -> partials, last block finalizes ----
  for (int off = 32; off > 0; off >>= 1)
    val += __shfl_down(val, off, 64);
  int lane = tid & 63, wid = tid >> 6;
  if (lane == 0) smem[wid] = val;
  __syncthreads();
  if (tid == 0) {
    partials[bid] = smem[0] + smem[1] + smem[2] + smem[3];
    __threadfence();  // release partials before signalling
    unsigned int old = atomicAdd(count, 1u);  // device scope by default
    amLast = (old == BLOCKS - 1);
  }
  __syncthreads();
  if (amLast) {
    __threadfence();  // acquire: invalidate L1 before reading partials
    double s = partials[tid] + partials[tid + THREADS];
    for (int off = 32; off > 0; off >>= 1)
      s += __shfl_down(s, off, 64);
    if (lane == 0) smem[wid] = s;
    __syncthreads();
    if (tid == 0)
      out[0] = (float)((smem[0] + smem[1] + smem[2] + smem[3]) /
                       (double)NPIX);
  }
}

extern "C" void kernel_launch(void* const* d_in, const int* in_sizes, int n_in,
                              void* d_out, int out_size, void* d_ws, size_t ws_size,
                              hipStream_t stream) {
  const float* input = (const float*)d_in[0];
  const int* target = (const int*)d_in[1];
  float* out = (float*)d_out;

  // workspace: [0,4KiB) partials[512]; count u32 at +4KiB; pw (128KiB) at +8KiB
  double* partials = (double*)d_ws;
  unsigned int* count = (unsigned int*)((char*)d_ws + 4096);
  unsigned long long* pw = (unsigned long long*)((char*)d_ws + 8192);

  void* args[] = {(void*)&target, (void*)&input, (void*)&pw,
                  (void*)&partials, (void*)&count, (void*)&out};
  hipLaunchCooperativeKernel((const void*)fused_all, dim3(BLOCKS), dim3(THREADS),
                             args, 0, stream);
}

// Round 2
// 74.991 us; speedup vs baseline: 1.6066x; 1.6066x over previous
//
#include <hip/hip_runtime.h>

#define H 1024
#define W 1024
#define NPIX (H * W)
#define WW 16          // 64-row words per column
#define INF_F 1e12f
#define THREADS 256
#define RBLOCKS 512    // 2 rows per block in the row kernel
#define BIG (1 << 29)

// ---------------------------------------------------------------------------
// Exact vertical nearest-site distance for pixel (r,c), polarity pol
// (pol=1: sites are 1-pixels; pol=0: sites are 0-pixels). Cold path.
// ---------------------------------------------------------------------------
__device__ __noinline__ int vert_dist_full(const unsigned long long* __restrict__ pw,
                                           int r, int c, int pol) {
  int w = r >> 6, b = r & 63;
  unsigned long long v = pw[w * W + c];
  unsigned long long m_c = pol ? v : ~v;
  int dup = 1 << 30, ddn = 1 << 30;
  unsigned long long am = m_c & ((1ULL << b) - 1ULL);
  if (am) {
    dup = b - (63 - __builtin_clzll(am));
  } else {
    for (int ww = w - 1; ww >= 0; --ww) {
      unsigned long long mv = pw[ww * W + c];
      mv = pol ? mv : ~mv;
      if (mv) { dup = r - (ww * 64 + 63 - __builtin_clzll(mv)); break; }
    }
  }
  unsigned long long bm = m_c >> b;  // includes self
  if (bm) {
    ddn = __builtin_ctzll(bm);
  } else {
    for (int ww = w + 1; ww < WW; ++ww) {
      unsigned long long mv = pw[ww * W + c];
      mv = pol ? mv : ~mv;
      if (mv) { ddn = (ww * 64 + __builtin_ctzll(mv)) - r; break; }
    }
  }
  return min(dup, ddn);
}

// Cold exact continuation/restart of the parabola min. Never taken at p=0.5.
__device__ __noinline__ int horiz_exact(const unsigned long long* __restrict__ pw,
                                        int r, int c, int pol, int best, int dk0) {
  for (int dk = dk0; dk < W; ++dk) {
    int dk2 = dk * dk;
    if (dk2 >= best) break;
    if (c - dk >= 0) {
      int d = vert_dist_full(pw, r, c - dk, pol);
      if (d < H) best = min(best, d * d + dk2);
    }
    if (c + dk < W) {
      int d = vert_dist_full(pw, r, c + dk, pol);
      if (d < H) best = min(best, d * d + dk2);
    }
  }
  return best;
}

// ---------------------------------------------------------------------------
// Kernel A: pack target (0/1 int32) into a bit matrix, column-major bits:
// pw[w*W + c] bit b = (target[(w*64+b)*W + c] != 0). u16 granularity for
// 2x thread parallelism vs the u32 version (65536 threads, 16 loads each).
// Also zeroes the last-block counter for kernel B.
// ---------------------------------------------------------------------------
__global__ __launch_bounds__(THREADS) void pack_bits(
    const int* __restrict__ target, unsigned short* __restrict__ pw16,
    unsigned int* __restrict__ count) {
  if (blockIdx.x == 0 && threadIdx.x == 0) *count = 0u;
  int tg = blockIdx.x * THREADS + threadIdx.x;  // [0, 65536)
  int c = tg & (W - 1);
  int rest = tg >> 10;        // [0, 64)
  int w = rest >> 2;
  int quarter = rest & 3;
  int rbase = w * 64 + quarter * 16;
  unsigned int val = 0;
#pragma unroll
  for (int b = 0; b < 16; ++b) {
    if (target[(rbase + b) * W + c] != 0) val |= (1u << b);
  }
  pw16[((w * W + c) << 2) + quarter] = (unsigned short)val;
}

// ---------------------------------------------------------------------------
// Kernel B: fused vertical EDT (bit ops) + horizontal parabola envelope (LDS
// bytes) + input*sd product + block reduction; the LAST-arriving block
// (device-scope atomic counter, no co-residency needed -> deadlock-safe
// under regular launch) reduces the 512 partials and writes the mean.
// 2 rows per block: rows 2q,2q+1 share the same 64-row word -> the pw
// window loads and border init are amortized across both rows.
// ---------------------------------------------------------------------------
__global__ __launch_bounds__(THREADS, 2) void fused_edt_row(
    const unsigned long long* __restrict__ pw,
    const float* __restrict__ input,
    double* __restrict__ partials,
    unsigned int* __restrict__ count,
    float* __restrict__ out) {
  // byte distances, [row][pol][32 + c]; 255 = "d >= 255" sentinel / pad
  __shared__ unsigned char sd8[2][2][W + 64];
  __shared__ double smem[THREADS / 64];
  __shared__ int amLast;
  const int tid = threadIdx.x;
  const int bid = blockIdx.x;
  const int r0 = bid << 1;           // rows r0, r0+1
  const int w = r0 >> 6;             // same word for both rows (r0 even)
  const int b0 = r0 & 63;            // even, so b0+1 <= 63
  const int c0 = tid << 2;           // 4 consecutive columns per thread

  // hoist the input loads: ~900cy HBM latency overlaps phase 1's VALU
  const float4 iv0 = *(const float4*)(input + r0 * W + c0);
  const float4 iv1 = *(const float4*)(input + (r0 + 1) * W + c0);

  // border init: 4 planes x 16 pad-u32 (8 left + 8 right per plane)
  if (tid < 64) {
    int p = tid >> 4, q = tid & 15;
    ((unsigned int*)sd8)[p * 272 + (q < 8 ? q : 256 + q)] = 0xFFFFFFFFu;
  }

  // ---- phase 1: vertical distances for 4 cols, 2 rows, both polarities ----
  unsigned long long curv[4], prevv[4], nextv[4];
  *(ulonglong2*)&curv[0] = *(const ulonglong2*)(pw + w * W + c0);
  *(ulonglong2*)&curv[2] = *(const ulonglong2*)(pw + w * W + c0 + 2);
  const bool hp = (w > 0), hn = (w < WW - 1);
  if (hp) {
    *(ulonglong2*)&prevv[0] = *(const ulonglong2*)(pw + (w - 1) * W + c0);
    *(ulonglong2*)&prevv[2] = *(const ulonglong2*)(pw + (w - 1) * W + c0 + 2);
  } else prevv[0] = prevv[1] = prevv[2] = prevv[3] = 0ULL;
  if (hn) {
    *(ulonglong2*)&nextv[0] = *(const ulonglong2*)(pw + (w + 1) * W + c0);
    *(ulonglong2*)&nextv[2] = *(const ulonglong2*)(pw + (w + 1) * W + c0 + 2);
  } else nextv[0] = nextv[1] = nextv[2] = nextv[3] = 0ULL;

  unsigned char dloc[2][2][4];  // [row][pol][k]
#pragma unroll
  for (int pol = 0; pol < 2; ++pol) {
#pragma unroll
    for (int k = 0; k < 4; ++k) {
      unsigned long long m_c = pol ? curv[k] : ~curv[k];
      unsigned long long m_p = hp ? (pol ? prevv[k] : ~prevv[k]) : 0ULL;
      unsigned long long m_n = hn ? (pol ? nextv[k] : ~nextv[k]) : 0ULL;
#pragma unroll
      for (int rr = 0; rr < 2; ++rr) {
        int b = b0 + rr;
        int d = 1 << 30;
        unsigned long long am = m_c & ((1ULL << b) - 1ULL);
        if (am) d = b - (63 - __builtin_clzll(am));
        else if (m_p) d = b + 1 + __builtin_clzll(m_p);
        unsigned long long bm = m_c >> b;  // includes self
        int dd = 1 << 30;
        if (bm) dd = __builtin_ctzll(bm);
        else if (m_n) dd = (64 - b) + __builtin_ctzll(m_n);
        d = min(d, dd);
        // window-blind (both directions) must be re-resolved exactly
        if (d > 64) d = vert_dist_full(pw, r0 + rr, c0 + k, pol);  // cold
        dloc[rr][pol][k] = (unsigned char)min(d, 255);
      }
    }
  }
  // LDS store: pack 4 col-bytes -> one u32 per (row,pol); conflict-free
#pragma unroll
  for (int rr = 0; rr < 2; ++rr) {
#pragma unroll
    for (int pol = 0; pol < 2; ++pol) {
      unsigned int u = (unsigned int)dloc[rr][pol][0] |
                       ((unsigned int)dloc[rr][pol][1] << 8) |
                       ((unsigned int)dloc[rr][pol][2] << 16) |
                       ((unsigned int)dloc[rr][pol][3] << 24);
      *(unsigned int*)&sd8[rr][pol][32 + c0] = u;
    }
  }
  __syncthreads();

  // ---- phase 2: horizontal envelope + product, both rows ----
  double val = 0.0;
#pragma unroll
  for (int rr = 0; rr < 2; ++rr) {
    const int r = r0 + rr;
    const float4 iv = rr ? iv1 : iv0;
    const float ivk[4] = {iv.x, iv.y, iv.z, iv.w};
#pragma unroll
    for (int k = 0; k < 4; ++k) {
      const bool t = (dloc[rr][1][k] == 0);  // nearest-one dist 0 <=> t=1
      const int pol = t ? 0 : 1;             // t uses g_t (nearest zero)
      const int own = dloc[rr][pol][k];
      int best = (own == 255) ? BIG : own * own;
      const unsigned char* __restrict__ sg = &sd8[rr][pol][32 + c0 + k];
#pragma unroll
      for (int dk = 1; dk <= 2; ++dk) {  // branchless probes, exactness-safe
        int dl = sg[-dk], dr = sg[dk];
        int gl = (dl == 255) ? BIG : dl * dl;
        int gr = (dr == 255) ? BIG : dr * dr;
        best = min(best, min(gl, gr) + dk * dk);
      }
      for (int dk = 3; dk <= 32; ++dk) {
        int dk2 = dk * dk;
        if (dk2 >= best) break;
        int dl = sg[-dk], dr = sg[dk];
        int gl = (dl == 255) ? BIG : dl * dl;
        int gr = (dr == 255) ? BIG : dr * dr;
        best = min(best, min(gl, gr) + dk2);
      }
      if (best > 1089) {  // cold exact fallback (beyond halo / sentinel)
        int c = c0 + k;
        if (best > 65025) {  // 255-sentinel could have hidden a true min
          int ov = vert_dist_full(pw, r, c, pol);
          best = (ov < H) ? ov * ov : (1 << 30);
          best = horiz_exact(pw, r, c, pol, best, 1);
        } else {
          best = horiz_exact(pw, r, c, pol, best, 33);
        }
      }
      float bestf = (best >= BIG) ? INF_F : (float)best;
      float dist = sqrtf(bestf);
      float sd = t ? (1.0f - dist) : dist;
      val += (double)(ivk[k] * sd);
    }
  }

  // ---- phase 3: block reduction -> partials; last block finalizes ----
  for (int off = 32; off > 0; off >>= 1)
    val += __shfl_down(val, off, 64);
  int lane = tid & 63, wid = tid >> 6;
  if (lane == 0) smem[wid] = val;
  __syncthreads();
  if (tid == 0) {
    partials[bid] = smem[0] + smem[1] + smem[2] + smem[3];
    __threadfence();  // release partials before signalling
    unsigned int old = atomicAdd(count, 1u);  // device scope by default
    amLast = (old == RBLOCKS - 1);
  }
  __syncthreads();
  if (amLast) {
    __threadfence();  // acquire: order reads of other blocks' partials
    double s = partials[tid] + partials[tid + THREADS];
    for (int off = 32; off > 0; off >>= 1)
      s += __shfl_down(s, off, 64);
    if (lane == 0) smem[wid] = s;
    __syncthreads();
    if (tid == 0)
      out[0] = (float)((smem[0] + smem[1] + smem[2] + smem[3]) /
                       (double)NPIX);
  }
}

extern "C" void kernel_launch(void* const* d_in, const int* in_sizes, int n_in,
                              void* d_out, int out_size, void* d_ws, size_t ws_size,
                              hipStream_t stream) {
  const float* input = (const float*)d_in[0];
  const int* target = (const int*)d_in[1];
  float* out = (float*)d_out;

  // workspace: [0,4KiB) partials[512]; count u32 at +4KiB; pw (128KiB) at +8KiB
  double* partials = (double*)d_ws;
  unsigned int* count = (unsigned int*)((char*)d_ws + 4096);
  unsigned long long* pw = (unsigned long long*)((char*)d_ws + 8192);

  pack_bits<<<256, THREADS, 0, stream>>>(target, (unsigned short*)pw, count);
  fused_edt_row<<<RBLOCKS, THREADS, 0, stream>>>(pw, input, partials, count, out);
}